// Round 4
// baseline (240.754 us; speedup 1.0000x reference)
//
#include <hip/hip_runtime.h>

// ScaledDotProductAttention B=2,H=16,S=2048,D=64 causal, f32 in/out (probed).
// v4: transposed QK (S^T = K·Q^T; A/B frags share lane layout so K-row loads
// are the A operand and Q regs the B operand). Probs land query-on-lane,
// keys-on-regs -> P->A-frag for PV is pack + 16 ds_bpermute per mr: NO LDS
// round-trip, no lgkmcnt drains in-loop. l = per-lane scalar, deferred.
// Raw v_exp_f32, softmax scale folded into Q. Split-K across 4 waves,
// 32 q-rows/block, 2048 blocks heavy-first. LDS only for final combine.

typedef __attribute__((ext_vector_type(8))) short  s8v;   // 8 x bf16
typedef __attribute__((ext_vector_type(4))) float  f4v;   // MFMA acc
typedef __attribute__((ext_vector_type(4))) unsigned int u4v;

#define SEQ 2048
#define DH  64
#define BHN 32
#define CSC 0.18033688f   // (1/sqrt(64)) * log2(e)

#if __has_builtin(__builtin_amdgcn_exp2f)
#define EXP2(x) __builtin_amdgcn_exp2f(x)
#else
#define EXP2(x) exp2f(x)
#endif

__device__ __forceinline__ unsigned short f2bf(float x) {
  union { float f; unsigned int u; } v; v.f = x;
  return (unsigned short)((v.u + 0x7fffu + ((v.u >> 16) & 1u)) >> 16);  // RNE
}
__device__ __forceinline__ float bf2f(unsigned short x) {
  union { unsigned int u; float f; } v; v.u = ((unsigned int)x) << 16;
  return v.f;
}
__device__ __forceinline__ bool probe_is_f32(const unsigned short* p) {
  const unsigned e = (p[threadIdx.x & 63] >> 7) & 0xFFu;
  return __ballot(e >= 0x89u) != 0ULL;
}
__device__ __forceinline__ s8v cvt8(const float* p) {
  float4 a = *(const float4*)p;
  float4 b = *(const float4*)(p + 4);
  s8v r;
  r[0] = (short)f2bf(a.x); r[1] = (short)f2bf(a.y);
  r[2] = (short)f2bf(a.z); r[3] = (short)f2bf(a.w);
  r[4] = (short)f2bf(b.x); r[5] = (short)f2bf(b.y);
  r[6] = (short)f2bf(b.z); r[7] = (short)f2bf(b.w);
  return r;
}
__device__ __forceinline__ s8v cvt8s(const float* p, float s) {
  float4 a = *(const float4*)p;
  float4 b = *(const float4*)(p + 4);
  s8v r;
  r[0] = (short)f2bf(a.x * s); r[1] = (short)f2bf(a.y * s);
  r[2] = (short)f2bf(a.z * s); r[3] = (short)f2bf(a.w * s);
  r[4] = (short)f2bf(b.x * s); r[5] = (short)f2bf(b.y * s);
  r[6] = (short)f2bf(b.z * s); r[7] = (short)f2bf(b.w * s);
  return r;
}

// ---- fused pre-pass: z=0 K->bf16 (same layout); z=1 V->Vt tiled transpose ----
__global__ __launch_bounds__(256) void prep_kernel(
    const void* __restrict__ Kv, const void* __restrict__ Vv,
    unsigned short* __restrict__ Kbf, unsigned short* __restrict__ Vt) {
  const int bh = blockIdx.y;
  const int s0 = blockIdx.x * 64;
  const int t  = threadIdx.x;
  if (blockIdx.z == 0) {
    const unsigned short* K16 = (const unsigned short*)Kv;
    const float*          KF  = (const float*)Kv;
    const bool isF32 = probe_is_f32(K16);
    const int sr = t >> 2, c0 = (t & 3) * 16;
    const size_t base = ((size_t)(bh * SEQ + s0 + sr)) * DH + c0;
    s8v a0, a1;
    if (!isF32) { a0 = *(const s8v*)(K16 + base); a1 = *(const s8v*)(K16 + base + 8); }
    else        { a0 = cvt8(KF + base);           a1 = cvt8(KF + base + 8); }
    *(s8v*)(Kbf + base)     = a0;
    *(s8v*)(Kbf + base + 8) = a1;
  } else {
    __shared__ __align__(16) unsigned short T[64][72];
    const unsigned short* V16 = (const unsigned short*)Vv;
    const float*          VF  = (const float*)Vv;
    const bool isF32 = probe_is_f32(V16);
    {
      const int sr = t >> 2, c0 = (t & 3) * 16;
      const size_t base = ((size_t)(bh * SEQ + s0 + sr)) * DH + c0;
      s8v a0, a1;
      if (!isF32) { a0 = *(const s8v*)(V16 + base); a1 = *(const s8v*)(V16 + base + 8); }
      else        { a0 = cvt8(VF + base);           a1 = cvt8(VF + base + 8); }
      *(s8v*)&T[sr][c0]     = a0;
      *(s8v*)&T[sr][c0 + 8] = a1;
    }
    __syncthreads();
    {
      const int d  = t & 63;
      const int sb = (t >> 6) * 16;
      unsigned int wb[8];
#pragma unroll
      for (int j = 0; j < 8; ++j) {
        unsigned int lo = T[sb + 2 * j][d];
        unsigned int hi = T[sb + 2 * j + 1][d];
        wb[j] = lo | (hi << 16);
      }
      // Vt[bh][s0/64][d][64]
      unsigned short* dst = Vt + (size_t)bh * SEQ * DH + (size_t)s0 * 64 + d * 64 + sb;
      u4v q0 = { wb[0], wb[1], wb[2], wb[3] };
      u4v q1 = { wb[4], wb[5], wb[6], wb[7] };
      *(u4v*)dst       = q0;
      *(u4v*)(dst + 8) = q1;
    }
  }
}

// ---- main: flash attention, transposed-QK + bpermute P, no in-loop LDS ----
__global__ __launch_bounds__(256, 4) void attn_kernel(
    const void* __restrict__ Qv, const unsigned short* __restrict__ Kbf,
    const unsigned short* __restrict__ Vt, void* __restrict__ Outv) {
  __shared__ __align__(16) unsigned short Ob[4][32][72];
  __shared__ float Lb[128];

  const unsigned short* Q16 = (const unsigned short*)Qv;
  const float*          QF  = (const float*)Qv;
  const bool isF32 = probe_is_f32(Q16);

  const int bh   = blockIdx.y;
  const int qt   = (gridDim.x - 1) - blockIdx.x;   // heavy blocks first
  const int q0   = qt * 32;
  const int tid  = threadIdx.x;
  const int w    = tid >> 6;
  const int lane = tid & 63;
  const int quad = lane >> 4;
  const int c16  = lane & 15;

  const size_t bh_off = (size_t)bh * SEQ * DH;
  const unsigned short* Kb = Kbf + bh_off;
  const unsigned short* Vb = Vt + bh_off;

  // Q fragments, prescaled by CSC (B-operand layout == A-operand layout)
  s8v aq[2][2];
#pragma unroll
  for (int mr = 0; mr < 2; ++mr)
#pragma unroll
    for (int kc = 0; kc < 2; ++kc) {
      const size_t idx = bh_off + (size_t)(q0 + mr * 16 + c16) * DH + kc * 32 + quad * 8;
      if (isF32) aq[mr][kc] = cvt8s(QF + idx, CSC);
      else {
        s8v a = *(const s8v*)(Q16 + idx);
#pragma unroll
        for (int j = 0; j < 8; ++j)
          a[j] = (short)f2bf(bf2f((unsigned short)a[j]) * CSC);
        aq[mr][kc] = a;
      }
    }

  f4v o[2][4];
  float l[2] = {0.f, 0.f};
#pragma unroll
  for (int mr = 0; mr < 2; ++mr)
#pragma unroll
    for (int i = 0; i < 4; ++i) { f4v z = {0.f, 0.f, 0.f, 0.f}; o[mr][i] = z; }

  // bpermute source-lane indices (bytes): src quad = 2*(q&1)+t, col c16
  const int idxt0 = 4 * (32 * (quad & 1) + c16);
  const int idxt1 = idxt0 + 64;
  const bool selHi = quad >= 2;      // pick nt = 2kc+1

  const int ntiles = qt / 2 + 1;

  for (int kt = w; kt < ntiles; kt += 4) {
    // K A-frags (issued first: QK waits vmcnt(8), V still in flight)
    s8v kb[4][2];
#pragma unroll
    for (int nt = 0; nt < 4; ++nt) {
      const unsigned short* kp = Kb + (size_t)(kt * 64 + nt * 16 + c16) * DH + quad * 8;
      kb[nt][0] = *(const s8v*)(kp);
      kb[nt][1] = *(const s8v*)(kp + 32);
    }
    // V B-frags from tiled Vt
    s8v vb[4][2];
    const unsigned short* vt0 = Vb + (size_t)kt * 4096;
#pragma unroll
    for (int dt = 0; dt < 4; ++dt) {
      const unsigned short* vp = vt0 + (dt * 16 + c16) * 64 + quad * 8;
      vb[dt][0] = *(const s8v*)(vp);
      vb[dt][1] = *(const s8v*)(vp + 32);
    }

    // S^T = K·Q^T: lane holds query=c16, keys=nt*16+quad*4+r
    float p[2][4][4];
#pragma unroll
    for (int mr = 0; mr < 2; ++mr)
#pragma unroll
      for (int nt = 0; nt < 4; ++nt) {
        f4v acc = {0.f, 0.f, 0.f, 0.f};
        acc = __builtin_amdgcn_mfma_f32_16x16x32_bf16(kb[nt][0], aq[mr][0], acc, 0, 0, 0);
        acc = __builtin_amdgcn_mfma_f32_16x16x32_bf16(kb[nt][1], aq[mr][1], acc, 0, 0, 0);
#pragma unroll
        for (int r = 0; r < 4; ++r) p[mr][nt][r] = EXP2(acc[r]);
      }
    // causal mask (diagonal tiles only; wave-uniform branch)
#pragma unroll
    for (int mr = 0; mr < 2; ++mr) {
      const int rbase = q0 + mr * 16;
      if (kt * 64 + 63 > rbase) {
        const int qmk = rbase + c16 - kt * 64 - quad * 4;  // key_local > qmk => mask
#pragma unroll
        for (int nt = 0; nt < 4; ++nt)
#pragma unroll
          for (int r = 0; r < 4; ++r)
            if (nt * 16 + r > qmk) p[mr][nt][r] = 0.f;
      }
    }
    // l accumulation (per-lane scalar, deferred reduction)
#pragma unroll
    for (int mr = 0; mr < 2; ++mr) {
      float s = 0.f;
#pragma unroll
      for (int nt = 0; nt < 4; ++nt)
        s += (p[mr][nt][0] + p[mr][nt][1]) + (p[mr][nt][2] + p[mr][nt][3]);
      l[mr] += s;
    }
    // pack + bpermute -> A-frags of P, then PV
#pragma unroll
    for (int mr = 0; mr < 2; ++mr) {
      int pk[4][2];
#pragma unroll
      for (int nt = 0; nt < 4; ++nt) {
        pk[nt][0] = (int)((unsigned)f2bf(p[mr][nt][0]) | ((unsigned)f2bf(p[mr][nt][1]) << 16));
        pk[nt][1] = (int)((unsigned)f2bf(p[mr][nt][2]) | ((unsigned)f2bf(p[mr][nt][3]) << 16));
      }
      s8v ap[2];
#pragma unroll
      for (int kc = 0; kc < 2; ++kc) {
        union { int d[4]; s8v v; } u;
#pragma unroll
        for (int d = 0; d < 4; ++d) {
          const int idx = (d >> 1) ? idxt1 : idxt0;
          const int h   = d & 1;
          int ta = __builtin_amdgcn_ds_bpermute(idx, pk[2 * kc][h]);
          int tb = __builtin_amdgcn_ds_bpermute(idx, pk[2 * kc + 1][h]);
          u.d[d] = selHi ? tb : ta;
        }
        ap[kc] = u.v;
      }
#pragma unroll
      for (int dt = 0; dt < 4; ++dt) {
        o[mr][dt] = __builtin_amdgcn_mfma_f32_16x16x32_bf16(ap[0], vb[dt][0], o[mr][dt], 0, 0, 0);
        o[mr][dt] = __builtin_amdgcn_mfma_f32_16x16x32_bf16(ap[1], vb[dt][1], o[mr][dt], 0, 0, 0);
      }
    }
  }

  // ---- cross-wave combine ----
#pragma unroll
  for (int mr = 0; mr < 2; ++mr) {
    float lv = l[mr];
    lv += __shfl_xor(lv, 16);
    lv += __shfl_xor(lv, 32);          // sum over quads; query = c16
    if (quad == 0) Lb[w * 32 + mr * 16 + c16] = lv;
#pragma unroll
    for (int dt = 0; dt < 4; ++dt)
#pragma unroll
      for (int r = 0; r < 4; ++r)
        Ob[w][mr * 16 + quad * 4 + r][dt * 16 + c16] = f2bf(o[mr][dt][r]);
  }
  __syncthreads();

  const int qrow = tid >> 3;
  const int cc   = (tid & 7) * 8;
  float a8[8] = {0.f, 0.f, 0.f, 0.f, 0.f, 0.f, 0.f, 0.f};
#pragma unroll
  for (int w2 = 0; w2 < 4; ++w2) {
    s8v ob = *(const s8v*)&Ob[w2][qrow][cc];
#pragma unroll
    for (int j = 0; j < 8; ++j) a8[j] += bf2f((unsigned short)ob[j]);
  }
  const float lt  = Lb[qrow] + Lb[32 + qrow] + Lb[64 + qrow] + Lb[96 + qrow];
  const float inv = 1.0f / lt;
  const size_t obase = bh_off + (size_t)(q0 + qrow) * DH + cc;
  if (isF32) {
    float* OF = (float*)Outv;
    float4 o0 = {a8[0] * inv, a8[1] * inv, a8[2] * inv, a8[3] * inv};
    float4 o1 = {a8[4] * inv, a8[5] * inv, a8[6] * inv, a8[7] * inv};
    *(float4*)(OF + obase)     = o0;
    *(float4*)(OF + obase + 4) = o1;
  } else {
    unsigned short* O16 = (unsigned short*)Outv;
    s8v ov;
#pragma unroll
    for (int j = 0; j < 8; ++j) ov[j] = (short)f2bf(a8[j] * inv);
    *(s8v*)(O16 + obase) = ov;
  }
}

extern "C" void kernel_launch(void* const* d_in, const int* in_sizes, int n_in,
                              void* d_out, int out_size, void* d_ws, size_t ws_size,
                              hipStream_t stream) {
  const void* Q = d_in[0];
  const void* K = d_in[1];
  const void* V = d_in[2];
  unsigned short* Kbf = (unsigned short*)d_ws;                     // 8.39 MB
  unsigned short* Vt  = Kbf + (size_t)BHN * SEQ * DH;              // 8.39 MB

  dim3 g1(SEQ / 64, BHN, 2);
  prep_kernel<<<g1, 256, 0, stream>>>(K, V, Kbf, Vt);
  dim3 g2(SEQ / 32, BHN);
  attn_kernel<<<g2, 256, 0, stream>>>(Q, Kbf, Vt, d_out);
}

// Round 5
// 175.943 us; speedup vs baseline: 1.3684x; 1.3684x over previous
//
#include <hip/hip_runtime.h>

// ScaledDotProductAttention B=2,H=16,S=2048,D=64 causal, f32 in/out (probed).
// v5 = v4 (transposed QK, bpermute P, deferred l — all verified passing) +
//  (a) launch_bounds(256,2): r4's launch_bounds(256,4) caused ~55MB scratch
//      spill in the K-loop (WRITE_SIZE 72MB vs 16.8MB output),
//  (b) XCD-clustered block swizzle: bh=(lin&7)*4+((lin>>3)&3) -> each XCD's
//      L2 holds only 4 bh of K/V (4MB, fits); r4 FETCH=130MB == 8x(K+V),
//  (c) software-pipelined K (register double-buffer, 2x-unrolled body for
//      static buffer indices) + V issued at iteration top -> loads have
//      ~1 iteration of flight time instead of stalling the chain.

typedef __attribute__((ext_vector_type(8))) short  s8v;   // 8 x bf16
typedef __attribute__((ext_vector_type(4))) float  f4v;   // MFMA acc
typedef __attribute__((ext_vector_type(4))) unsigned int u4v;

#define SEQ 2048
#define DH  64
#define BHN 32
#define CSC 0.18033688f   // (1/sqrt(64)) * log2(e)

#if __has_builtin(__builtin_amdgcn_exp2f)
#define EXP2(x) __builtin_amdgcn_exp2f(x)
#else
#define EXP2(x) exp2f(x)
#endif

__device__ __forceinline__ unsigned short f2bf(float x) {
  union { float f; unsigned int u; } v; v.f = x;
  return (unsigned short)((v.u + 0x7fffu + ((v.u >> 16) & 1u)) >> 16);  // RNE
}
__device__ __forceinline__ float bf2f(unsigned short x) {
  union { unsigned int u; float f; } v; v.u = ((unsigned int)x) << 16;
  return v.f;
}
__device__ __forceinline__ bool probe_is_f32(const unsigned short* p) {
  const unsigned e = (p[threadIdx.x & 63] >> 7) & 0xFFu;
  return __ballot(e >= 0x89u) != 0ULL;
}
__device__ __forceinline__ s8v cvt8(const float* p) {
  float4 a = *(const float4*)p;
  float4 b = *(const float4*)(p + 4);
  s8v r;
  r[0] = (short)f2bf(a.x); r[1] = (short)f2bf(a.y);
  r[2] = (short)f2bf(a.z); r[3] = (short)f2bf(a.w);
  r[4] = (short)f2bf(b.x); r[5] = (short)f2bf(b.y);
  r[6] = (short)f2bf(b.z); r[7] = (short)f2bf(b.w);
  return r;
}
__device__ __forceinline__ s8v cvt8s(const float* p, float s) {
  float4 a = *(const float4*)p;
  float4 b = *(const float4*)(p + 4);
  s8v r;
  r[0] = (short)f2bf(a.x * s); r[1] = (short)f2bf(a.y * s);
  r[2] = (short)f2bf(a.z * s); r[3] = (short)f2bf(a.w * s);
  r[4] = (short)f2bf(b.x * s); r[5] = (short)f2bf(b.y * s);
  r[6] = (short)f2bf(b.z * s); r[7] = (short)f2bf(b.w * s);
  return r;
}

// ---- fused pre-pass: z=0 K->bf16 (same layout); z=1 V->Vt tiled transpose ----
__global__ __launch_bounds__(256) void prep_kernel(
    const void* __restrict__ Kv, const void* __restrict__ Vv,
    unsigned short* __restrict__ Kbf, unsigned short* __restrict__ Vt) {
  const int bh = blockIdx.y;
  const int s0 = blockIdx.x * 64;
  const int t  = threadIdx.x;
  if (blockIdx.z == 0) {
    const unsigned short* K16 = (const unsigned short*)Kv;
    const float*          KF  = (const float*)Kv;
    const bool isF32 = probe_is_f32(K16);
    const int sr = t >> 2, c0 = (t & 3) * 16;
    const size_t base = ((size_t)(bh * SEQ + s0 + sr)) * DH + c0;
    s8v a0, a1;
    if (!isF32) { a0 = *(const s8v*)(K16 + base); a1 = *(const s8v*)(K16 + base + 8); }
    else        { a0 = cvt8(KF + base);           a1 = cvt8(KF + base + 8); }
    *(s8v*)(Kbf + base)     = a0;
    *(s8v*)(Kbf + base + 8) = a1;
  } else {
    __shared__ __align__(16) unsigned short T[64][72];
    const unsigned short* V16 = (const unsigned short*)Vv;
    const float*          VF  = (const float*)Vv;
    const bool isF32 = probe_is_f32(V16);
    {
      const int sr = t >> 2, c0 = (t & 3) * 16;
      const size_t base = ((size_t)(bh * SEQ + s0 + sr)) * DH + c0;
      s8v a0, a1;
      if (!isF32) { a0 = *(const s8v*)(V16 + base); a1 = *(const s8v*)(V16 + base + 8); }
      else        { a0 = cvt8(VF + base);           a1 = cvt8(VF + base + 8); }
      *(s8v*)&T[sr][c0]     = a0;
      *(s8v*)&T[sr][c0 + 8] = a1;
    }
    __syncthreads();
    {
      const int d  = t & 63;
      const int sb = (t >> 6) * 16;
      unsigned int wb[8];
#pragma unroll
      for (int j = 0; j < 8; ++j) {
        unsigned int lo = T[sb + 2 * j][d];
        unsigned int hi = T[sb + 2 * j + 1][d];
        wb[j] = lo | (hi << 16);
      }
      unsigned short* dst = Vt + (size_t)bh * SEQ * DH + (size_t)s0 * 64 + d * 64 + sb;
      u4v q0 = { wb[0], wb[1], wb[2], wb[3] };
      u4v q1 = { wb[4], wb[5], wb[6], wb[7] };
      *(u4v*)dst       = q0;
      *(u4v*)(dst + 8) = q1;
    }
  }
}

// ---- main: flash attention, pipelined K, XCD-clustered swizzle ----
__global__ __launch_bounds__(256, 2) void attn_kernel(
    const void* __restrict__ Qv, const unsigned short* __restrict__ Kbf,
    const unsigned short* __restrict__ Vt, void* __restrict__ Outv) {
  __shared__ __align__(16) unsigned short Ob[4][32][72];
  __shared__ float Lb[128];

  const unsigned short* Q16 = (const unsigned short*)Qv;
  const float*          QF  = (const float*)Qv;
  const bool isF32 = probe_is_f32(Q16);

  // swizzle: heavy qt first; bh clustered 4-per-XCD (linear%8 ~ XCD)
  const int linear = blockIdx.x;
  const int qt = 63 - (linear >> 5);
  const int j  = linear & 31;
  const int bh = (j & 7) * 4 + (j >> 3);
  const int q0 = qt * 32;

  const int tid  = threadIdx.x;
  const int w    = tid >> 6;
  const int lane = tid & 63;
  const int quad = lane >> 4;
  const int c16  = lane & 15;

  const size_t bh_off = (size_t)bh * SEQ * DH;
  const unsigned short* Kb = Kbf + bh_off;
  const unsigned short* Vb = Vt + bh_off;

  // Q fragments, prescaled by CSC (B-operand layout == A-operand layout)
  s8v aq[2][2];
#pragma unroll
  for (int mr = 0; mr < 2; ++mr)
#pragma unroll
    for (int kc = 0; kc < 2; ++kc) {
      const size_t idx = bh_off + (size_t)(q0 + mr * 16 + c16) * DH + kc * 32 + quad * 8;
      if (isF32) aq[mr][kc] = cvt8s(QF + idx, CSC);
      else {
        s8v a = *(const s8v*)(Q16 + idx);
#pragma unroll
        for (int jj = 0; jj < 8; ++jj)
          a[jj] = (short)f2bf(bf2f((unsigned short)a[jj]) * CSC);
        aq[mr][kc] = a;
      }
    }

  f4v o[2][4];
  float l[2] = {0.f, 0.f};
#pragma unroll
  for (int mr = 0; mr < 2; ++mr)
#pragma unroll
    for (int i = 0; i < 4; ++i) { f4v z = {0.f, 0.f, 0.f, 0.f}; o[mr][i] = z; }

  // bpermute source-lane indices (bytes)
  const int idxt0 = 4 * (32 * (quad & 1) + c16);
  const int idxt1 = idxt0 + 64;
  const bool selHi = quad >= 2;

  const int ntiles = qt / 2 + 1;

  s8v kbA[4][2], kbB[4][2];   // K double-buffer (static indices)

  auto loadK = [&](s8v (&dst)[4][2], int kt) {
    const unsigned short* kbase = Kb + (size_t)kt * 64 * DH;
#pragma unroll
    for (int nt = 0; nt < 4; ++nt) {
      const unsigned short* kp = kbase + (nt * 16 + c16) * DH + quad * 8;
      dst[nt][0] = *(const s8v*)(kp);
      dst[nt][1] = *(const s8v*)(kp + 32);
    }
  };

  auto body = [&](const s8v (&cur)[4][2], s8v (&nxt)[4][2], int kt) {
    // V loads issued first (consumed after ~2 softmax blocks)
    s8v vb[4][2];
    const unsigned short* vt0 = Vb + (size_t)kt * 4096;
#pragma unroll
    for (int dt = 0; dt < 4; ++dt) {
      const unsigned short* vp = vt0 + (dt * 16 + c16) * 64 + quad * 8;
      vb[dt][0] = *(const s8v*)(vp);
      vb[dt][1] = *(const s8v*)(vp + 32);
    }
    // K prefetch for kt+4 (full iteration of flight time)
    if (kt + 4 < ntiles) loadK(nxt, kt + 4);

    s8v ap[2][2];
#pragma unroll
    for (int mr = 0; mr < 2; ++mr) {
      float p[4][4];
#pragma unroll
      for (int nt = 0; nt < 4; ++nt) {
        f4v acc = {0.f, 0.f, 0.f, 0.f};
        acc = __builtin_amdgcn_mfma_f32_16x16x32_bf16(cur[nt][0], aq[mr][0], acc, 0, 0, 0);
        acc = __builtin_amdgcn_mfma_f32_16x16x32_bf16(cur[nt][1], aq[mr][1], acc, 0, 0, 0);
#pragma unroll
        for (int r = 0; r < 4; ++r) p[nt][r] = EXP2(acc[r]);
      }
      const int rbase = q0 + mr * 16;
      if (kt * 64 + 63 > rbase) {  // diagonal tiles: zero masked probs
        const int qmk = rbase + c16 - kt * 64 - quad * 4;
#pragma unroll
        for (int nt = 0; nt < 4; ++nt)
#pragma unroll
          for (int r = 0; r < 4; ++r)
            if (nt * 16 + r > qmk) p[mr == mr ? nt : nt][r] = 0.f,
                                   p[nt][r] = 0.f;
      }
      float s = 0.f;
#pragma unroll
      for (int nt = 0; nt < 4; ++nt)
        s += (p[nt][0] + p[nt][1]) + (p[nt][2] + p[nt][3]);
      l[mr] += s;
      // pack + bpermute -> A-frags of P
      int pk[4][2];
#pragma unroll
      for (int nt = 0; nt < 4; ++nt) {
        pk[nt][0] = (int)((unsigned)f2bf(p[nt][0]) | ((unsigned)f2bf(p[nt][1]) << 16));
        pk[nt][1] = (int)((unsigned)f2bf(p[nt][2]) | ((unsigned)f2bf(p[nt][3]) << 16));
      }
#pragma unroll
      for (int kc = 0; kc < 2; ++kc) {
        union { int d[4]; s8v v; } u;
#pragma unroll
        for (int d = 0; d < 4; ++d) {
          const int idx = (d >> 1) ? idxt1 : idxt0;
          const int h   = d & 1;
          int ta = __builtin_amdgcn_ds_bpermute(idx, pk[2 * kc][h]);
          int tb = __builtin_amdgcn_ds_bpermute(idx, pk[2 * kc + 1][h]);
          u.d[d] = selHi ? tb : ta;
        }
        ap[mr][kc] = u.v;
      }
    }
#pragma unroll
    for (int mr = 0; mr < 2; ++mr)
#pragma unroll
      for (int dt = 0; dt < 4; ++dt) {
        o[mr][dt] = __builtin_amdgcn_mfma_f32_16x16x32_bf16(ap[mr][0], vb[dt][0], o[mr][dt], 0, 0, 0);
        o[mr][dt] = __builtin_amdgcn_mfma_f32_16x16x32_bf16(ap[mr][1], vb[dt][1], o[mr][dt], 0, 0, 0);
      }
  };

  int kt = w;
  if (kt < ntiles) {
    loadK(kbA, kt);
    while (true) {
      body(kbA, kbB, kt);
      kt += 4; if (kt >= ntiles) break;
      body(kbB, kbA, kt);
      kt += 4; if (kt >= ntiles) break;
    }
  }

  // ---- cross-wave combine ----
#pragma unroll
  for (int mr = 0; mr < 2; ++mr) {
    float lv = l[mr];
    lv += __shfl_xor(lv, 16);
    lv += __shfl_xor(lv, 32);
    if (quad == 0) Lb[w * 32 + mr * 16 + c16] = lv;
#pragma unroll
    for (int dt = 0; dt < 4; ++dt)
#pragma unroll
      for (int r = 0; r < 4; ++r)
        Ob[w][mr * 16 + quad * 4 + r][dt * 16 + c16] = f2bf(o[mr][dt][r]);
  }
  __syncthreads();

  const int qrow = tid >> 3;
  const int cc   = (tid & 7) * 8;
  float a8[8] = {0.f, 0.f, 0.f, 0.f, 0.f, 0.f, 0.f, 0.f};
#pragma unroll
  for (int w2 = 0; w2 < 4; ++w2) {
    s8v ob = *(const s8v*)&Ob[w2][qrow][cc];
#pragma unroll
    for (int jj = 0; jj < 8; ++jj) a8[jj] += bf2f((unsigned short)ob[jj]);
  }
  const float lt  = Lb[qrow] + Lb[32 + qrow] + Lb[64 + qrow] + Lb[96 + qrow];
  const float inv = 1.0f / lt;
  const size_t obase = bh_off + (size_t)(q0 + qrow) * DH + cc;
  if (isF32) {
    float* OF = (float*)Outv;
    float4 o0 = {a8[0] * inv, a8[1] * inv, a8[2] * inv, a8[3] * inv};
    float4 o1 = {a8[4] * inv, a8[5] * inv, a8[6] * inv, a8[7] * inv};
    *(float4*)(OF + obase)     = o0;
    *(float4*)(OF + obase + 4) = o1;
  } else {
    unsigned short* O16 = (unsigned short*)Outv;
    s8v ov;
#pragma unroll
    for (int jj = 0; jj < 8; ++jj) ov[jj] = (short)f2bf(a8[jj] * inv);
    *(s8v*)(O16 + obase) = ov;
  }
}

extern "C" void kernel_launch(void* const* d_in, const int* in_sizes, int n_in,
                              void* d_out, int out_size, void* d_ws, size_t ws_size,
                              hipStream_t stream) {
  const void* Q = d_in[0];
  const void* K = d_in[1];
  const void* V = d_in[2];
  unsigned short* Kbf = (unsigned short*)d_ws;                     // 8.39 MB
  unsigned short* Vt  = Kbf + (size_t)BHN * SEQ * DH;              // 8.39 MB

  dim3 g1(SEQ / 64, BHN, 2);
  prep_kernel<<<g1, 256, 0, stream>>>(K, V, Kbf, Vt);
  attn_kernel<<<dim3(2048), 256, 0, stream>>>(Q, Kbf, Vt, d_out);
}

// Round 6
// 150.447 us; speedup vs baseline: 1.6003x; 1.1695x over previous
//
#include <hip/hip_runtime.h>
#include <hip/hip_bf16.h>

// ScaledDotProductAttention B=2,H=16,S=2048,D=64 causal, f32 in/out (probed).
// v6: r5 was L2/L3-read-BW bound (540MB of per-wave K/V tile re-reads at
// ~6.5TB/s = the 83us). Fix: block-cooperative LDS staging — 4 waves share
// each K/V tile (waves split q: 128 q-rows/block, 32/wave, NO split-K, no
// cross-wave combine). Traffic /4 -> ~70MB. Double-buffered LDS, loads at
// iter top / ds_writes after compute / 1 barrier per iter. Work-balanced
// grid: block pairs (qb, 15-qb) => every CU's 2 resident blocks sum to 34
// iters. Keeps r5's validated transposed-QK + bpermute-P + deferred-l math.
// VALU cut: __float22bfloat162_rn packed bf16 convert.

typedef __attribute__((ext_vector_type(8))) short  s8v;   // 8 x bf16
typedef __attribute__((ext_vector_type(4))) float  f4v;   // MFMA acc
typedef __attribute__((ext_vector_type(4))) unsigned int u4v;

#define SEQ 2048
#define DH  64
#define BHN 32
#define CSC 0.18033688f   // (1/sqrt(64)) * log2(e)

#if __has_builtin(__builtin_amdgcn_exp2f)
#define EXP2(x) __builtin_amdgcn_exp2f(x)
#else
#define EXP2(x) exp2f(x)
#endif

__device__ __forceinline__ unsigned short f2bf(float x) {
  union { float f; unsigned int u; } v; v.f = x;
  return (unsigned short)((v.u + 0x7fffu + ((v.u >> 16) & 1u)) >> 16);  // RNE
}
__device__ __forceinline__ float bf2f(unsigned short x) {
  union { unsigned int u; float f; } v; v.u = ((unsigned int)x) << 16;
  return v.f;
}
__device__ __forceinline__ int pack_bf2(float a, float b) {
  union { __hip_bfloat162 h; int i; } u;
  u.h = __float22bfloat162_rn(make_float2(a, b));   // a->low, b->high
  return u.i;
}
__device__ __forceinline__ bool probe_is_f32(const unsigned short* p) {
  const unsigned e = (p[threadIdx.x & 63] >> 7) & 0xFFu;
  return __ballot(e >= 0x89u) != 0ULL;
}
__device__ __forceinline__ s8v cvt8(const float* p) {
  float4 a = *(const float4*)p;
  float4 b = *(const float4*)(p + 4);
  s8v r;
  r[0] = (short)f2bf(a.x); r[1] = (short)f2bf(a.y);
  r[2] = (short)f2bf(a.z); r[3] = (short)f2bf(a.w);
  r[4] = (short)f2bf(b.x); r[5] = (short)f2bf(b.y);
  r[6] = (short)f2bf(b.z); r[7] = (short)f2bf(b.w);
  return r;
}
__device__ __forceinline__ s8v cvt8s(const float* p, float s) {
  float4 a = *(const float4*)p;
  float4 b = *(const float4*)(p + 4);
  s8v r;
  r[0] = (short)f2bf(a.x * s); r[1] = (short)f2bf(a.y * s);
  r[2] = (short)f2bf(a.z * s); r[3] = (short)f2bf(a.w * s);
  r[4] = (short)f2bf(b.x * s); r[5] = (short)f2bf(b.y * s);
  r[6] = (short)f2bf(b.z * s); r[7] = (short)f2bf(b.w * s);
  return r;
}

// ---- fused pre-pass: z=0 K->bf16 (same layout); z=1 V->Vt tiled transpose ----
__global__ __launch_bounds__(256) void prep_kernel(
    const void* __restrict__ Kv, const void* __restrict__ Vv,
    unsigned short* __restrict__ Kbf, unsigned short* __restrict__ Vt) {
  const int bh = blockIdx.y;
  const int s0 = blockIdx.x * 64;
  const int t  = threadIdx.x;
  if (blockIdx.z == 0) {
    const unsigned short* K16 = (const unsigned short*)Kv;
    const float*          KF  = (const float*)Kv;
    const bool isF32 = probe_is_f32(K16);
    const int sr = t >> 2, c0 = (t & 3) * 16;
    const size_t base = ((size_t)(bh * SEQ + s0 + sr)) * DH + c0;
    s8v a0, a1;
    if (!isF32) { a0 = *(const s8v*)(K16 + base); a1 = *(const s8v*)(K16 + base + 8); }
    else        { a0 = cvt8(KF + base);           a1 = cvt8(KF + base + 8); }
    *(s8v*)(Kbf + base)     = a0;
    *(s8v*)(Kbf + base + 8) = a1;
  } else {
    __shared__ __align__(16) unsigned short T[64][72];
    const unsigned short* V16 = (const unsigned short*)Vv;
    const float*          VF  = (const float*)Vv;
    const bool isF32 = probe_is_f32(V16);
    {
      const int sr = t >> 2, c0 = (t & 3) * 16;
      const size_t base = ((size_t)(bh * SEQ + s0 + sr)) * DH + c0;
      s8v a0, a1;
      if (!isF32) { a0 = *(const s8v*)(V16 + base); a1 = *(const s8v*)(V16 + base + 8); }
      else        { a0 = cvt8(VF + base);           a1 = cvt8(VF + base + 8); }
      *(s8v*)&T[sr][c0]     = a0;
      *(s8v*)&T[sr][c0 + 8] = a1;
    }
    __syncthreads();
    {
      const int d  = t & 63;
      const int sb = (t >> 6) * 16;
      unsigned int wb[8];
#pragma unroll
      for (int j = 0; j < 8; ++j) {
        unsigned int lo = T[sb + 2 * j][d];
        unsigned int hi = T[sb + 2 * j + 1][d];
        wb[j] = lo | (hi << 16);
      }
      unsigned short* dst = Vt + (size_t)bh * SEQ * DH + (size_t)s0 * 64 + d * 64 + sb;
      u4v q0 = { wb[0], wb[1], wb[2], wb[3] };
      u4v q1 = { wb[4], wb[5], wb[6], wb[7] };
      *(u4v*)dst       = q0;
      *(u4v*)(dst + 8) = q1;
    }
  }
}

// ---- main: flash attention, LDS-shared K/V tiles, waves split q ----
__global__ __launch_bounds__(256, 2) void attn_kernel(
    const void* __restrict__ Qv, const unsigned short* __restrict__ Kbf,
    const unsigned short* __restrict__ Vt, void* __restrict__ Outv) {
  __shared__ __align__(16) unsigned short Ks[2][64][72];   // [buf][key][d]
  __shared__ __align__(16) unsigned short Vs[2][64][72];   // [buf][d][key]

  const unsigned short* Q16 = (const unsigned short*)Qv;
  const float*          QF  = (const float*)Qv;
  const bool isF32 = probe_is_f32(Q16);

  // grid 512: pair qb with 15-qb -> constant work per CU (2 blocks sum 34 iters)
  const int blk = blockIdx.x;
  const int pr  = blk >> 5;
  const int qb  = (pr < 8) ? (15 - pr) : (pr - 8);
  const int bj  = blk & 31;
  const int bh  = (bj & 7) * 4 + (bj >> 3);            // XCD-clustered K/V reuse

  const int tid  = threadIdx.x;
  const int w    = tid >> 6;
  const int lane = tid & 63;
  const int quad = lane >> 4;
  const int c16  = lane & 15;
  const int q0   = qb * 128 + w * 32;                  // this wave's 32 q-rows

  const size_t bh_off = (size_t)bh * SEQ * DH;
  const unsigned short* Kb = Kbf + bh_off;
  const unsigned short* Vb = Vt  + bh_off;

  // Q fragments, prescaled by CSC (B-operand layout == A-operand layout)
  s8v aq[2][2];
#pragma unroll
  for (int mr = 0; mr < 2; ++mr)
#pragma unroll
    for (int kc = 0; kc < 2; ++kc) {
      const size_t idx = bh_off + (size_t)(q0 + mr * 16 + c16) * DH + kc * 32 + quad * 8;
      if (isF32) aq[mr][kc] = cvt8s(QF + idx, CSC);
      else {
        s8v a = *(const s8v*)(Q16 + idx);
#pragma unroll
        for (int t = 0; t < 8; ++t)
          a[t] = (short)f2bf(bf2f((unsigned short)a[t]) * CSC);
        aq[mr][kc] = a;
      }
    }

  f4v o[2][4];
  float l[2] = {0.f, 0.f};
#pragma unroll
  for (int mr = 0; mr < 2; ++mr)
#pragma unroll
    for (int i = 0; i < 4; ++i) { f4v z = {0.f, 0.f, 0.f, 0.f}; o[mr][i] = z; }

  // bpermute source-lane indices (bytes) — validated r4/r5 mapping
  const int idxt0 = 4 * (32 * (quad & 1) + c16);
  const int idxt1 = idxt0 + 64;
  const bool selHi = quad >= 2;

  const int ntiles = 2 * qb + 2;

  // staging: thread -> 32B of K row and 32B of V row (tile stride 64*DH shorts)
  const int srow = tid >> 2;
  const int scol = (tid & 3) * 16;
  const unsigned short* Kst = Kb + (size_t)srow * DH + scol;
  const unsigned short* Vst = Vb + (size_t)srow * 64 + scol;

  { // prologue: stage tile 0 into buf 0
    s8v k0 = *(const s8v*)(Kst), k1 = *(const s8v*)(Kst + 8);
    s8v v0 = *(const s8v*)(Vst), v1 = *(const s8v*)(Vst + 8);
    *(s8v*)&Ks[0][srow][scol]     = k0;
    *(s8v*)&Ks[0][srow][scol + 8] = k1;
    *(s8v*)&Vs[0][srow][scol]     = v0;
    *(s8v*)&Vs[0][srow][scol + 8] = v1;
  }
  __syncthreads();

  for (int kt = 0; kt < ntiles; ++kt) {
    const int cb = kt & 1, nb = cb ^ 1;
    // issue next tile's global loads now; ds_write after compute
    const size_t koff = (size_t)((kt + 1 < ntiles) ? kt + 1 : 0) * (64 * DH);
    s8v nk0 = *(const s8v*)(Kst + koff), nk1 = *(const s8v*)(Kst + koff + 8);
    s8v nv0 = *(const s8v*)(Vst + koff), nv1 = *(const s8v*)(Vst + koff + 8);

    if (kt * 64 <= q0 + 31) {   // wave-uniform: any of my rows attend this tile
      // K A-frags from LDS (2-way banks = free)
      s8v kb[4][2];
#pragma unroll
      for (int nt = 0; nt < 4; ++nt) {
        kb[nt][0] = *(const s8v*)&Ks[cb][nt * 16 + c16][quad * 8];
        kb[nt][1] = *(const s8v*)&Ks[cb][nt * 16 + c16][32 + quad * 8];
      }
      s8v ap[2][2];
      bool act[2];
#pragma unroll
      for (int mr = 0; mr < 2; ++mr) {
        const int rbase = q0 + mr * 16;
        act[mr] = (kt * 64 <= rbase + 15);
        if (!act[mr]) continue;
        // S^T = K·Q^T: lane holds query=c16, keys=nt*16+quad*4+r
        float p[4][4];
#pragma unroll
        for (int nt = 0; nt < 4; ++nt) {
          f4v acc = {0.f, 0.f, 0.f, 0.f};
          acc = __builtin_amdgcn_mfma_f32_16x16x32_bf16(kb[nt][0], aq[mr][0], acc, 0, 0, 0);
          acc = __builtin_amdgcn_mfma_f32_16x16x32_bf16(kb[nt][1], aq[mr][1], acc, 0, 0, 0);
#pragma unroll
          for (int r = 0; r < 4; ++r) p[nt][r] = EXP2(acc[r]);  // no-max: f32-safe
        }
        if (kt * 64 + 63 > rbase) {  // diagonal tile: zero masked probs
          const int qmk = rbase + c16 - kt * 64 - quad * 4;
#pragma unroll
          for (int nt = 0; nt < 4; ++nt)
#pragma unroll
            for (int r = 0; r < 4; ++r)
              if (nt * 16 + r > qmk) p[nt][r] = 0.f;
        }
        float s = 0.f;
#pragma unroll
        for (int nt = 0; nt < 4; ++nt)
          s += (p[nt][0] + p[nt][1]) + (p[nt][2] + p[nt][3]);
        l[mr] += s;
        // pack pairs (packed cvt) + bpermute -> P A-frags
        int pk[4][2];
#pragma unroll
        for (int nt = 0; nt < 4; ++nt) {
          pk[nt][0] = pack_bf2(p[nt][0], p[nt][1]);
          pk[nt][1] = pack_bf2(p[nt][2], p[nt][3]);
        }
#pragma unroll
        for (int kc = 0; kc < 2; ++kc) {
          union { int d[4]; s8v v; } u;
#pragma unroll
          for (int d = 0; d < 4; ++d) {
            const int idx = (d >> 1) ? idxt1 : idxt0;
            const int h   = d & 1;
            int ta = __builtin_amdgcn_ds_bpermute(idx, pk[2 * kc][h]);
            int tb = __builtin_amdgcn_ds_bpermute(idx, pk[2 * kc + 1][h]);
            u.d[d] = selHi ? tb : ta;
          }
          ap[mr][kc] = u.v;
        }
      }
      // V B-frags from LDS, then PV
      s8v vb[4][2];
#pragma unroll
      for (int dt = 0; dt < 4; ++dt) {
        vb[dt][0] = *(const s8v*)&Vs[cb][dt * 16 + c16][quad * 8];
        vb[dt][1] = *(const s8v*)&Vs[cb][dt * 16 + c16][32 + quad * 8];
      }
#pragma unroll
      for (int mr = 0; mr < 2; ++mr) {
        if (!act[mr]) continue;
#pragma unroll
        for (int dt = 0; dt < 4; ++dt) {
          o[mr][dt] = __builtin_amdgcn_mfma_f32_16x16x32_bf16(ap[mr][0], vb[dt][0], o[mr][dt], 0, 0, 0);
          o[mr][dt] = __builtin_amdgcn_mfma_f32_16x16x32_bf16(ap[mr][1], vb[dt][1], o[mr][dt], 0, 0, 0);
        }
      }
    }
    // stage next tile (other buffer) and barrier once
    *(s8v*)&Ks[nb][srow][scol]     = nk0;
    *(s8v*)&Ks[nb][srow][scol + 8] = nk1;
    *(s8v*)&Vs[nb][srow][scol]     = nv0;
    *(s8v*)&Vs[nb][srow][scol + 8] = nv1;
    __syncthreads();
  }

  // ---- epilogue: wave-local (no cross-wave combine needed) ----
#pragma unroll
  for (int mr = 0; mr < 2; ++mr) {
    float lv = l[mr];
    lv += __shfl_xor(lv, 16);
    lv += __shfl_xor(lv, 32);     // l(query=c16), replicated over quads
    union { float f; int i; } lu; lu.f = lv;
    float invr[4];
#pragma unroll
    for (int rr = 0; rr < 4; ++rr) {
      union { int i; float f; } tf;
      tf.i = __builtin_amdgcn_ds_bpermute(4 * (quad * 4 + rr), lu.i);
      invr[rr] = 1.0f / tf.f;     // l for my output row quad*4+rr
    }
    if (isF32) {
      float* OF = (float*)Outv;
#pragma unroll
      for (int rr = 0; rr < 4; ++rr) {
        const size_t rb = bh_off + (size_t)(q0 + mr * 16 + quad * 4 + rr) * DH + c16;
#pragma unroll
        for (int dt = 0; dt < 4; ++dt)
          OF[rb + dt * 16] = o[mr][dt][rr] * invr[rr];
      }
    } else {
      unsigned short* O16 = (unsigned short*)Outv;
#pragma unroll
      for (int rr = 0; rr < 4; ++rr) {
        const size_t rb = bh_off + (size_t)(q0 + mr * 16 + quad * 4 + rr) * DH + c16;
#pragma unroll
        for (int dt = 0; dt < 4; ++dt)
          O16[rb + dt * 16] = f2bf(o[mr][dt][rr] * invr[rr]);
      }
    }
  }
}

extern "C" void kernel_launch(void* const* d_in, const int* in_sizes, int n_in,
                              void* d_out, int out_size, void* d_ws, size_t ws_size,
                              hipStream_t stream) {
  const void* Q = d_in[0];
  const void* K = d_in[1];
  const void* V = d_in[2];
  unsigned short* Kbf = (unsigned short*)d_ws;                     // 8.39 MB
  unsigned short* Vt  = Kbf + (size_t)BHN * SEQ * DH;              // 8.39 MB

  dim3 g1(SEQ / 64, BHN, 2);
  prep_kernel<<<g1, 256, 0, stream>>>(K, V, Kbf, Vt);
  attn_kernel<<<dim3(512), 256, 0, stream>>>(Q, Kbf, Vt, d_out);
}

// Round 7
// 144.027 us; speedup vs baseline: 1.6716x; 1.0446x over previous
//
#include <hip/hip_runtime.h>
#include <hip/hip_bf16.h>

// ScaledDotProductAttention B=2,H=16,S=2048,D=64 causal, f32 in/out (probed).
// v7: r6 was DS-pipe bound (~650 DS-cyc/wave-iter: 16 b128 frag reads +
// 32 ds_bpermute + staging). Fix: sigma-permuted contraction — MFMA's k-dim
// is order-agnostic if A and B agree. With sigma(quad,j)=(j>=4?16:0)+4*quad+(j&3):
//   * P A-frag = in-lane packs of p[nt][r] (ZERO cross-lane ops),
//   * V B-frag = two contiguous ds_read_b64 from Vs[d][key] rows.
// DS/wave-iter drops to ~240 cyc (8 b128 K + 16 b64 V + 4 b128 staging).
// Everything else = r6 (LDS-shared tiles, waves split q, paired-qb balance,
// XCD-clustered bh, no-max softmax with deferred l, Q prescaled by CSC).

typedef __attribute__((ext_vector_type(8))) short  s8v;   // 8 x bf16
typedef __attribute__((ext_vector_type(4))) short  s4v;   // 4 x bf16 (b64)
typedef __attribute__((ext_vector_type(4))) float  f4v;   // MFMA acc
typedef __attribute__((ext_vector_type(4))) unsigned int u4v;

#define SEQ 2048
#define DH  64
#define BHN 32
#define CSC 0.18033688f   // (1/sqrt(64)) * log2(e)

#if __has_builtin(__builtin_amdgcn_exp2f)
#define EXP2(x) __builtin_amdgcn_exp2f(x)
#else
#define EXP2(x) exp2f(x)
#endif

__device__ __forceinline__ unsigned short f2bf(float x) {
  union { float f; unsigned int u; } v; v.f = x;
  return (unsigned short)((v.u + 0x7fffu + ((v.u >> 16) & 1u)) >> 16);  // RNE
}
__device__ __forceinline__ float bf2f(unsigned short x) {
  union { unsigned int u; float f; } v; v.u = ((unsigned int)x) << 16;
  return v.f;
}
__device__ __forceinline__ int pack_bf2(float a, float b) {
  union { __hip_bfloat162 h; int i; } u;
  u.h = __float22bfloat162_rn(make_float2(a, b));   // a->low, b->high
  return u.i;
}
__device__ __forceinline__ bool probe_is_f32(const unsigned short* p) {
  const unsigned e = (p[threadIdx.x & 63] >> 7) & 0xFFu;
  return __ballot(e >= 0x89u) != 0ULL;
}
__device__ __forceinline__ s8v cvt8(const float* p) {
  float4 a = *(const float4*)p;
  float4 b = *(const float4*)(p + 4);
  s8v r;
  r[0] = (short)f2bf(a.x); r[1] = (short)f2bf(a.y);
  r[2] = (short)f2bf(a.z); r[3] = (short)f2bf(a.w);
  r[4] = (short)f2bf(b.x); r[5] = (short)f2bf(b.y);
  r[6] = (short)f2bf(b.z); r[7] = (short)f2bf(b.w);
  return r;
}
__device__ __forceinline__ s8v cvt8s(const float* p, float s) {
  float4 a = *(const float4*)p;
  float4 b = *(const float4*)(p + 4);
  s8v r;
  r[0] = (short)f2bf(a.x * s); r[1] = (short)f2bf(a.y * s);
  r[2] = (short)f2bf(a.z * s); r[3] = (short)f2bf(a.w * s);
  r[4] = (short)f2bf(b.x * s); r[5] = (short)f2bf(b.y * s);
  r[6] = (short)f2bf(b.z * s); r[7] = (short)f2bf(b.w * s);
  return r;
}

// ---- fused pre-pass: z=0 K->bf16 (same layout); z=1 V->Vt tiled transpose ----
__global__ __launch_bounds__(256) void prep_kernel(
    const void* __restrict__ Kv, const void* __restrict__ Vv,
    unsigned short* __restrict__ Kbf, unsigned short* __restrict__ Vt) {
  const int bh = blockIdx.y;
  const int s0 = blockIdx.x * 64;
  const int t  = threadIdx.x;
  if (blockIdx.z == 0) {
    const unsigned short* K16 = (const unsigned short*)Kv;
    const float*          KF  = (const float*)Kv;
    const bool isF32 = probe_is_f32(K16);
    const int sr = t >> 2, c0 = (t & 3) * 16;
    const size_t base = ((size_t)(bh * SEQ + s0 + sr)) * DH + c0;
    s8v a0, a1;
    if (!isF32) { a0 = *(const s8v*)(K16 + base); a1 = *(const s8v*)(K16 + base + 8); }
    else        { a0 = cvt8(KF + base);           a1 = cvt8(KF + base + 8); }
    *(s8v*)(Kbf + base)     = a0;
    *(s8v*)(Kbf + base + 8) = a1;
  } else {
    __shared__ __align__(16) unsigned short T[64][72];
    const unsigned short* V16 = (const unsigned short*)Vv;
    const float*          VF  = (const float*)Vv;
    const bool isF32 = probe_is_f32(V16);
    {
      const int sr = t >> 2, c0 = (t & 3) * 16;
      const size_t base = ((size_t)(bh * SEQ + s0 + sr)) * DH + c0;
      s8v a0, a1;
      if (!isF32) { a0 = *(const s8v*)(V16 + base); a1 = *(const s8v*)(V16 + base + 8); }
      else        { a0 = cvt8(VF + base);           a1 = cvt8(VF + base + 8); }
      *(s8v*)&T[sr][c0]     = a0;
      *(s8v*)&T[sr][c0 + 8] = a1;
    }
    __syncthreads();
    {
      const int d  = t & 63;
      const int sb = (t >> 6) * 16;
      unsigned int wb[8];
#pragma unroll
      for (int j = 0; j < 8; ++j) {
        unsigned int lo = T[sb + 2 * j][d];
        unsigned int hi = T[sb + 2 * j + 1][d];
        wb[j] = lo | (hi << 16);
      }
      unsigned short* dst = Vt + (size_t)bh * SEQ * DH + (size_t)s0 * 64 + d * 64 + sb;
      u4v q0 = { wb[0], wb[1], wb[2], wb[3] };
      u4v q1 = { wb[4], wb[5], wb[6], wb[7] };
      *(u4v*)dst       = q0;
      *(u4v*)(dst + 8) = q1;
    }
  }
}

// ---- main: flash attention, sigma-permuted PV, LDS-shared K/V tiles ----
__global__ __launch_bounds__(256, 2) void attn_kernel(
    const void* __restrict__ Qv, const unsigned short* __restrict__ Kbf,
    const unsigned short* __restrict__ Vt, void* __restrict__ Outv) {
  __shared__ __align__(16) unsigned short Ks[2][64][72];   // [buf][key][d]
  __shared__ __align__(16) unsigned short Vs[2][64][72];   // [buf][d][key]

  const unsigned short* Q16 = (const unsigned short*)Qv;
  const float*          QF  = (const float*)Qv;
  const bool isF32 = probe_is_f32(Q16);

  // grid 512: pair qb with 15-qb -> constant work per CU (2 blocks sum 34 iters)
  const int blk = blockIdx.x;
  const int pr  = blk >> 5;
  const int qb  = (pr < 8) ? (15 - pr) : (pr - 8);
  const int bj  = blk & 31;
  const int bh  = (bj & 7) * 4 + (bj >> 3);            // XCD-clustered K/V reuse

  const int tid  = threadIdx.x;
  const int w    = tid >> 6;
  const int lane = tid & 63;
  const int quad = lane >> 4;
  const int c16  = lane & 15;
  const int q0   = qb * 128 + w * 32;                  // this wave's 32 q-rows

  const size_t bh_off = (size_t)bh * SEQ * DH;
  const unsigned short* Kb = Kbf + bh_off;
  const unsigned short* Vb = Vt  + bh_off;

  // Q fragments, prescaled by CSC (B-operand layout == A-operand layout)
  s8v aq[2][2];
#pragma unroll
  for (int mr = 0; mr < 2; ++mr)
#pragma unroll
    for (int kc = 0; kc < 2; ++kc) {
      const size_t idx = bh_off + (size_t)(q0 + mr * 16 + c16) * DH + kc * 32 + quad * 8;
      if (isF32) aq[mr][kc] = cvt8s(QF + idx, CSC);
      else {
        s8v a = *(const s8v*)(Q16 + idx);
#pragma unroll
        for (int t = 0; t < 8; ++t)
          a[t] = (short)f2bf(bf2f((unsigned short)a[t]) * CSC);
        aq[mr][kc] = a;
      }
    }

  f4v o[2][4];
  float l[2] = {0.f, 0.f};
#pragma unroll
  for (int mr = 0; mr < 2; ++mr)
#pragma unroll
    for (int i = 0; i < 4; ++i) { f4v z = {0.f, 0.f, 0.f, 0.f}; o[mr][i] = z; }

  const int ntiles = 2 * qb + 2;

  // staging: thread -> 32B of K row and 32B of V row (tile stride 64*DH shorts)
  const int srow = tid >> 2;
  const int scol = (tid & 3) * 16;
  const unsigned short* Kst = Kb + (size_t)srow * DH + scol;
  const unsigned short* Vst = Vb + (size_t)srow * 64 + scol;

  { // prologue: stage tile 0 into buf 0
    s8v k0 = *(const s8v*)(Kst), k1 = *(const s8v*)(Kst + 8);
    s8v v0 = *(const s8v*)(Vst), v1 = *(const s8v*)(Vst + 8);
    *(s8v*)&Ks[0][srow][scol]     = k0;
    *(s8v*)&Ks[0][srow][scol + 8] = k1;
    *(s8v*)&Vs[0][srow][scol]     = v0;
    *(s8v*)&Vs[0][srow][scol + 8] = v1;
  }
  __syncthreads();

  for (int kt = 0; kt < ntiles; ++kt) {
    const int cb = kt & 1, nb = cb ^ 1;
    // issue next tile's global loads now; ds_write after compute
    const size_t koff = (size_t)((kt + 1 < ntiles) ? kt + 1 : 0) * (64 * DH);
    s8v nk0 = *(const s8v*)(Kst + koff), nk1 = *(const s8v*)(Kst + koff + 8);
    s8v nv0 = *(const s8v*)(Vst + koff), nv1 = *(const s8v*)(Vst + koff + 8);

    if (kt * 64 <= q0 + 31) {   // wave-uniform: any of my rows attend this tile
      // K A-frags from LDS
      s8v kb[4][2];
#pragma unroll
      for (int nt = 0; nt < 4; ++nt) {
        kb[nt][0] = *(const s8v*)&Ks[cb][nt * 16 + c16][quad * 8];
        kb[nt][1] = *(const s8v*)&Ks[cb][nt * 16 + c16][32 + quad * 8];
      }
      // V B-frags via sigma: keys kc*32 + {4*quad..+3, 16+4*quad..+3}
      s8v vb[4][2];
#pragma unroll
      for (int dt = 0; dt < 4; ++dt)
#pragma unroll
        for (int kc = 0; kc < 2; ++kc) {
          const unsigned short* vr = &Vs[cb][dt * 16 + c16][kc * 32 + quad * 4];
          union { s4v h[2]; s8v v; } uv;
          uv.h[0] = *(const s4v*)(vr);        // keys +0..3   (j=0..3)
          uv.h[1] = *(const s4v*)(vr + 16);   // keys +16..19 (j=4..7)
          vb[dt][kc] = uv.v;
        }

#pragma unroll
      for (int mr = 0; mr < 2; ++mr) {
        const int rbase = q0 + mr * 16;
        if (kt * 64 > rbase + 15) continue;   // wave-uniform per mr
        // S^T = K·Q^T: lane holds query=c16, keys=nt*16+quad*4+r
        float p[4][4];
#pragma unroll
        for (int nt = 0; nt < 4; ++nt) {
          f4v acc = {0.f, 0.f, 0.f, 0.f};
          acc = __builtin_amdgcn_mfma_f32_16x16x32_bf16(kb[nt][0], aq[mr][0], acc, 0, 0, 0);
          acc = __builtin_amdgcn_mfma_f32_16x16x32_bf16(kb[nt][1], aq[mr][1], acc, 0, 0, 0);
#pragma unroll
          for (int r = 0; r < 4; ++r) p[nt][r] = EXP2(acc[r]);  // no-max: f32-safe
        }
        if (kt * 64 + 63 > rbase) {  // diagonal tile: zero masked probs
          const int qmk = rbase + c16 - kt * 64 - quad * 4;
#pragma unroll
          for (int nt = 0; nt < 4; ++nt)
#pragma unroll
            for (int r = 0; r < 4; ++r)
              if (nt * 16 + r > qmk) p[nt][r] = 0.f;
        }
        float s = 0.f;
#pragma unroll
        for (int nt = 0; nt < 4; ++nt)
          s += (p[nt][0] + p[nt][1]) + (p[nt][2] + p[nt][3]);
        l[mr] += s;
        // P A-frags: pure in-lane pack (sigma ordering), zero cross-lane ops
#pragma unroll
        for (int kc = 0; kc < 2; ++kc) {
          union { int d[4]; s8v v; } u;
          u.d[0] = pack_bf2(p[2 * kc][0],     p[2 * kc][1]);
          u.d[1] = pack_bf2(p[2 * kc][2],     p[2 * kc][3]);
          u.d[2] = pack_bf2(p[2 * kc + 1][0], p[2 * kc + 1][1]);
          u.d[3] = pack_bf2(p[2 * kc + 1][2], p[2 * kc + 1][3]);
          // PV: O += P·V (k-permutation sigma shared by A and B)
#pragma unroll
          for (int dt = 0; dt < 4; ++dt)
            o[mr][dt] = __builtin_amdgcn_mfma_f32_16x16x32_bf16(u.v, vb[dt][kc], o[mr][dt], 0, 0, 0);
        }
      }
    }
    // stage next tile (other buffer) and barrier once
    *(s8v*)&Ks[nb][srow][scol]     = nk0;
    *(s8v*)&Ks[nb][srow][scol + 8] = nk1;
    *(s8v*)&Vs[nb][srow][scol]     = nv0;
    *(s8v*)&Vs[nb][srow][scol + 8] = nv1;
    __syncthreads();
  }

  // ---- epilogue: wave-local ----
#pragma unroll
  for (int mr = 0; mr < 2; ++mr) {
    float lv = l[mr];
    lv += __shfl_xor(lv, 16);
    lv += __shfl_xor(lv, 32);     // l(query=c16), replicated over quads
    union { float f; int i; } lu; lu.f = lv;
    float invr[4];
#pragma unroll
    for (int rr = 0; rr < 4; ++rr) {
      union { int i; float f; } tf;
      tf.i = __builtin_amdgcn_ds_bpermute(4 * (quad * 4 + rr), lu.i);
      invr[rr] = 1.0f / tf.f;     // l for my output row quad*4+rr
    }
    if (isF32) {
      float* OF = (float*)Outv;
#pragma unroll
      for (int rr = 0; rr < 4; ++rr) {
        const size_t rb = bh_off + (size_t)(q0 + mr * 16 + quad * 4 + rr) * DH + c16;
#pragma unroll
        for (int dt = 0; dt < 4; ++dt)
          OF[rb + dt * 16] = o[mr][dt][rr] * invr[rr];
      }
    } else {
      unsigned short* O16 = (unsigned short*)Outv;
#pragma unroll
      for (int rr = 0; rr < 4; ++rr) {
        const size_t rb = bh_off + (size_t)(q0 + mr * 16 + quad * 4 + rr) * DH + c16;
#pragma unroll
        for (int dt = 0; dt < 4; ++dt)
          O16[rb + dt * 16] = f2bf(o[mr][dt][rr] * invr[rr]);
      }
    }
  }
}

extern "C" void kernel_launch(void* const* d_in, const int* in_sizes, int n_in,
                              void* d_out, int out_size, void* d_ws, size_t ws_size,
                              hipStream_t stream) {
  const void* Q = d_in[0];
  const void* K = d_in[1];
  const void* V = d_in[2];
  unsigned short* Kbf = (unsigned short*)d_ws;                     // 8.39 MB
  unsigned short* Vt  = Kbf + (size_t)BHN * SEQ * DH;              // 8.39 MB

  dim3 g1(SEQ / 64, BHN, 2);
  prep_kernel<<<g1, 256, 0, stream>>>(K, V, Kbf, Vt);
  attn_kernel<<<dim3(512), 256, 0, stream>>>(Q, Kbf, Vt, d_out);
}